// Round 14
// baseline (7249.723 us; speedup 1.0000x reference)
//
#include <hip/hip_runtime.h>
#include <math.h>

namespace {
constexpr int B_ = 128;
constexpr int T_ = 256;
constexpr int D_ = 512;
constexpr int U_ = 1024;
constexpr int N3U = 3 * U_;        // 3072
constexpr int K_TOT = D_ + U_;     // 1536
constexpr int WROWS = 48;          // 3 gates x 16 u
constexpr int ROWB = 3088;         // LDS row stride bytes: (1536+8)*2
constexpr int EXCH_OFF = WROWS * ROWB;           // 148224
constexpr int LDS_BYTES = EXCH_OFF + 12288;      // 160512
constexpr int POLL_LIM = 1 << 20;
}

#define E_CONST 2.71828182845904523536f

using bf16x8 = __attribute__((ext_vector_type(8))) short;
using f32x4  = __attribute__((ext_vector_type(4))) float;

__device__ inline unsigned short f2bf(float f) {
    union { float f; unsigned int u; } a; a.f = f;
    unsigned int u = a.u;
    return (unsigned short)((u + 0x7FFFu + ((u >> 16) & 1u)) >> 16);  // RNE
}

__device__ inline bf16x8 cvt8(const float* src) {
    float v[8];
    *reinterpret_cast<float4*>(&v[0]) = *reinterpret_cast<const float4*>(src);
    *reinterpret_cast<float4*>(&v[4]) = *reinterpret_cast<const float4*>(src + 4);
    bf16x8 r;
    #pragma unroll
    for (int j = 0; j < 8; ++j) r[j] = (short)f2bf(v[j]);
    return r;
}

// 16 coherent (L1/L2-bypass, L3-served) 16B loads at base + j*64 bytes.
#define ISSUE16(arr, base)                                                     \
    {                                                                          \
        _Pragma("unroll")                                                      \
        for (int j = 0; j < 16; ++j) {                                         \
            asm volatile("global_load_dwordx4 %0, %1, off offset:%2 sc0 sc1"   \
                         : "=&v"(arr[j])                                       \
                         : "v"(base), "i"(j * 64));                            \
        }                                                                      \
    }
#define PIN16(arr)                                                             \
    {                                                                          \
        _Pragma("unroll")                                                      \
        for (int j = 0; j < 16; ++j) asm volatile("" : "+v"(arr[j]));          \
    }
#define WAITV0 asm volatile("s_waitcnt vmcnt(0)" ::: "memory")

// ---- one-time prep: WcatT[n][k] = bf16( k<512 ? Wk[k][n] : Wr[k-512][n] ) ----
__global__ void wprep(const float* __restrict__ Wk, const float* __restrict__ Wr,
                      unsigned short* __restrict__ WcatT) {
    __shared__ unsigned short S[32][33];
    const int kb = blockIdx.x * 32;
    const int nb = blockIdx.y * 32;
    const int tx = threadIdx.x;
    const int ty = threadIdx.y;
    #pragma unroll
    for (int j = 0; j < 4; ++j) {
        const int r = ty + 8 * j;
        const int k = kb + r;
        const int n = nb + tx;
        const float v = (k < D_) ? Wk[(size_t)k * N3U + n]
                                 : Wr[(size_t)(k - D_) * N3U + n];
        S[tx][r] = f2bf(v);
    }
    __syncthreads();
    #pragma unroll
    for (int j = 0; j < 4; ++j) {
        const int r = ty + 8 * j;
        WcatT[(size_t)(nb + r) * K_TOT + kb + tx] = S[r][tx];
    }
}

// ---- one-time prep: decays[b][t] = 1/log(e + dt) ----
__global__ void dprep(const float* __restrict__ dts, float* __restrict__ decays) {
    const int i = blockIdx.x * 256 + threadIdx.x;
    if (i < B_ * T_) decays[i] = 1.0f / logf(E_CONST + dts[i]);
}

// ---- persistent kernel: R9 protocol + own-half flags + u-half pipelined wait ----
// 256 blocks (XCD-clustered), 512 thr = 8 waves.
// Waves 0-5 (bt = w&1, gate g = w>>1): x-GEMM, then self-poll flags of the 32
//   producers of each u-half (own row-half flag only) and gather+MFMA pipelined.
// Waves 6-7 (bt = w-6): decay prefetch; epilogue; publish; vmcnt(0); flag.
__global__ __launch_bounds__(512) void tgru_flags5(
    const float* __restrict__ seq,            // [B,T,D] fp32
    const float* __restrict__ decays,         // [B,T]
    const unsigned short* __restrict__ WcatT, // [3072][1536] bf16
    const float* __restrict__ ib,             // [3U]
    const float* __restrict__ rb,             // [3U]
    unsigned short* hbA,                      // h*dec bf16 (h at even t)
    unsigned short* hbB,                      // h at odd t
    unsigned int* flags,                      // [NBG*64] x 16 u32 (64B lines)
    float* __restrict__ out)                  // [B,U]
{
    extern __shared__ char lds[];

    const int tid  = threadIdx.x;
    const int lane = tid & 63;
    const int w    = tid >> 6;
    const int l15  = lane & 15;
    const int lk   = lane >> 4;
    const int bid  = blockIdx.x;
    const int bg   = (bid >> 1) & 3;                 // XCD-clustered group
    const int ub   = ((bid >> 3) << 1) | (bid & 1);  // 0..63
    const int u0   = ub * 16;

    // ---- stage weights: 48 rows x 1536 k into LDS (padded rows) ----
    for (int idx = tid; idx < WROWS * 192; idx += 512) {
        const int c = idx / 192;          // row 0..47
        const int o = idx % 192;          // 16B chunk
        const unsigned short* src =
            WcatT + (size_t)((c >> 4) * U_ + u0 + (c & 15)) * K_TOT + o * 8;
        *reinterpret_cast<bf16x8*>(lds + (size_t)c * ROWB + o * 16) =
            *reinterpret_cast<const bf16x8*>(src);
    }
    __syncthreads();

    float* exf = reinterpret_cast<float*>(lds + EXCH_OFF);

    // ---- epilogue-wave constants ----
    const int up = lane & 7;          // u-pair index
    const int rg = lane >> 3;         // 0..7 row-group
    float bzs[2], brs[2], ibh_[2], rbh_[2];
    float hreg[2][2] = {{0.f, 0.f}, {0.f, 0.f}};
    if (w >= 6) {
        #pragma unroll
        for (int f = 0; f < 2; ++f) {
            const int u = u0 + 2 * up + f;
            bzs[f]  = ib[u] + rb[u];
            brs[f]  = ib[U_ + u] + rb[U_ + u];
            ibh_[f] = ib[2 * U_ + u];
            rbh_[f] = rb[2 * U_ + u];
        }
    }
    unsigned int* myflag = flags + ((bg << 6) + ub) * 16 + (w - 6);
    // GEMM-wave poll addresses: producer p = lane&31 (+32 for half 1), own bt flag
    const int bt_g = w & 1;
    const unsigned int* fp0 = flags + ((bg << 6) + (lane & 31)) * 16 + bt_g;
    const unsigned int* fp1 = flags + ((bg << 6) + 32 + (lane & 31)) * 16 + bt_g;

    #pragma unroll 1
    for (int t = 0; t < T_; ++t) {
        const unsigned short* hbp = (t & 1) ? hbB : hbA;   // h(t)
        unsigned short*       hbn = (t & 1) ? hbA : hbB;   // h(t+1)
        float decn[2];

        f32x4 aX = {0.f, 0.f, 0.f, 0.f};
        f32x4 aH = {0.f, 0.f, 0.f, 0.f};
        const char* wrow = lds + (size_t)((w >> 1) * 16 + l15) * ROWB + 16 * lk;
        const int bgemm = bg * 32 + bt_g * 16 + l15;

        if (w < 6) {
            // ---- x-GEMM (k in [0,512)) — fills time before h(t) arrives ----
            const float* ap = seq + ((size_t)bgemm * T_ + t) * D_ + 8 * lk;
            #pragma unroll 8
            for (int ks = 0; ks < 16; ++ks) {
                const bf16x8 a = cvt8(ap + 32 * ks);
                const bf16x8 bf = *reinterpret_cast<const bf16x8*>(wrow + 64 * ks);
                aX = __builtin_amdgcn_mfma_f32_16x16x32_bf16(a, bf, aX, 0, 0, 0);
            }

            if (t > 0) {
                const char* hbase = (const char*)(hbp + (size_t)bgemm * U_ + 8 * lk);
                bf16x8 hv0[16], hv1[16];

                // poll u-half 0 producers (own row-half flag only)
                {
                    int guard = 0;
                    for (;;) {
                        const unsigned int v = __hip_atomic_load(
                            fp0, __ATOMIC_RELAXED, __HIP_MEMORY_SCOPE_AGENT);
                        if (__all((int)(v >= (unsigned int)t))) break;
                        if (++guard > POLL_LIM) break;
                    }
                }
                ISSUE16(hv0, hbase)          // half-0 gather in flight

                // poll u-half 1 (its internal waitcnt also drains hv0's flight)
                {
                    int guard = 0;
                    for (;;) {
                        const unsigned int v = __hip_atomic_load(
                            fp1, __ATOMIC_RELAXED, __HIP_MEMORY_SCOPE_AGENT);
                        if (__all((int)(v >= (unsigned int)t))) break;
                        if (++guard > POLL_LIM) break;
                    }
                }
                __builtin_amdgcn_fence(__ATOMIC_ACQUIRE, "workgroup");
                ISSUE16(hv1, hbase + 1024)   // half-1 gather under half-0 MFMAs

                PIN16(hv0)                   // hv0 complete (poll drained vmcnt)
                #pragma unroll 8
                for (int j = 0; j < 16; ++j) {
                    const bf16x8 bf = *reinterpret_cast<const bf16x8*>(
                        wrow + 1024 + 64 * j);
                    aH = __builtin_amdgcn_mfma_f32_16x16x32_bf16(hv0[j], bf, aH, 0, 0, 0);
                }
                WAITV0; PIN16(hv1)
                #pragma unroll 8
                for (int j = 0; j < 16; ++j) {
                    const bf16x8 bf = *reinterpret_cast<const bf16x8*>(
                        wrow + 2048 + 64 * j);
                    aH = __builtin_amdgcn_mfma_f32_16x16x32_bf16(hv1[j], bf, aH, 0, 0, 0);
                }
            }
            *reinterpret_cast<f32x4*>(&exf[w * 512 + lane * 4]) = aX;
            *reinterpret_cast<f32x4*>(&exf[w * 512 + 256 + lane * 4]) = aH;
        } else {
            // decay prefetch for t+1
            const int tn = (t < T_ - 1) ? t + 1 : t;
            #pragma unroll
            for (int e = 0; e < 2; ++e) {
                const int b = bg * 32 + (w - 6) * 16 + rg * 2 + e;
                decn[e] = decays[b * T_ + tn];
            }
        }

        __syncthreads();   // B2: exchange ready

        if (w >= 6) {
            const int bt = w - 6;
            #pragma unroll
            for (int e = 0; e < 2; ++e) {
                const int bl  = rg * 2 + e;
                const int b   = bg * 32 + bt * 16 + bl;
                const int lkq = (bl >> 2) * 16;
                const int q   = bl & 3;
                float hn2[2];
                #pragma unroll
                for (int f = 0; f < 2; ++f) {
                    const int ul = 2 * up + f;
                    const int i0 = (0 * 2 + bt) * 512 + (lkq + ul) * 4 + q;
                    const int i1 = (1 * 2 + bt) * 512 + (lkq + ul) * 4 + q;
                    const int i2 = (2 * 2 + bt) * 512 + (lkq + ul) * 4 + q;
                    const float z  = 1.0f / (1.0f + expf(-(exf[i0] + exf[i0 + 256] + bzs[f])));
                    const float r  = 1.0f / (1.0f + expf(-(exf[i1] + exf[i1 + 256] + brs[f])));
                    const float hh = tanhf(exf[i2] + ibh_[f] + r * (exf[i2 + 256] + rbh_[f]));
                    hn2[f] = z * hreg[e][f] + (1.0f - z) * hh;
                }
                if (t == T_ - 1) {
                    *reinterpret_cast<float2*>(&out[(size_t)b * U_ + u0 + 2 * up]) =
                        make_float2(hn2[0], hn2[1]);
                } else {
                    const float hd0 = hn2[0] * decn[e];
                    const float hd1 = hn2[1] * decn[e];
                    hreg[e][0] = hd0;     // fp32 state stays in regs
                    hreg[e][1] = hd1;
                    const unsigned int pk =
                        (unsigned int)f2bf(hd0) | ((unsigned int)f2bf(hd1) << 16);
                    __hip_atomic_store(
                        reinterpret_cast<unsigned int*>(&hbn[(size_t)b * U_ + u0 + 2 * up]),
                        pk, __ATOMIC_RELAXED, __HIP_MEMORY_SCOPE_AGENT);
                }
            }
            if (t < T_ - 1) {
                WAITV0;   // h stores at L3 (merging path — 70 MB proven, R9)
                if (lane == 0) {
                    __hip_atomic_store(myflag, (unsigned int)(t + 1),
                                       __ATOMIC_RELAXED, __HIP_MEMORY_SCOPE_AGENT);
                }
            }
        }

        __syncthreads();   // B3: exf free for next step's writers
    }
}

extern "C" void kernel_launch(void* const* d_in, const int* in_sizes, int n_in,
                              void* d_out, int out_size, void* d_ws, size_t ws_size,
                              hipStream_t stream) {
    const float* seq = (const float*)d_in[0];
    const float* dts = (const float*)d_in[1];
    const float* Wk  = (const float*)d_in[2];
    const float* Wr  = (const float*)d_in[3];
    const float* ib  = (const float*)d_in[4];
    const float* rb  = (const float*)d_in[5];
    float* out = (float*)d_out;

    char* wsb = (char*)d_ws;
    // ws layout (bytes):
    //   [0,        9437184)   WcatT bf16 [3072][1536]
    //   [9437184,  9568256)   decays fp32 [128][256]
    //   [9568256,  9830400)   hbA bf16 [128][1024]  (not read at t=0)
    //   [9830400, 10092544)   hbB
    //   [10092544,10108928)   flags: 256 blocks x 64 B
    unsigned short* wcat   = (unsigned short*)(wsb);
    float*          decays = (float*)(wsb + 9437184);
    unsigned short* hbA    = (unsigned short*)(wsb + 9568256);
    unsigned short* hbB    = (unsigned short*)(wsb + 9830400);
    unsigned int*   flags  = (unsigned int*)(wsb + 10092544);

    // flags must be 0 at start of every replay (monotonic within a launch)
    hipMemsetAsync(flags, 0, 16384, stream);

    wprep<<<dim3(K_TOT / 32, N3U / 32), dim3(32, 8), 0, stream>>>(Wk, Wr, wcat);
    dprep<<<dim3((B_ * T_ + 255) / 256), dim3(256), 0, stream>>>(dts, decays);

    hipFuncSetAttribute((const void*)tgru_flags5,
                        hipFuncAttributeMaxDynamicSharedMemorySize, LDS_BYTES);

    tgru_flags5<<<dim3(256), dim3(512), LDS_BYTES, stream>>>(
        seq, decays, wcat, ib, rb, hbA, hbB, flags, out);
}

// Round 15
// 3097.658 us; speedup vs baseline: 2.3404x; 2.3404x over previous
//
#include <hip/hip_runtime.h>
#include <math.h>

namespace {
constexpr int B_ = 128;
constexpr int T_ = 256;
constexpr int D_ = 512;
constexpr int U_ = 1024;
constexpr int N3U = 3 * U_;        // 3072
constexpr int K_TOT = D_ + U_;     // 1536
constexpr int WROWS = 48;          // 3 gates x 16 u
constexpr int ROWB = 3088;         // LDS row stride bytes: (1536+8)*2
constexpr int LDS_BYTES = WROWS * ROWB;   // 148224
constexpr int POLL_LIM = 1 << 20;
}

#define E_CONST 2.71828182845904523536f

using bf16x8 = __attribute__((ext_vector_type(8))) short;
using f32x4  = __attribute__((ext_vector_type(4))) float;

__device__ inline unsigned short f2bf(float f) {
    union { float f; unsigned int u; } a; a.f = f;
    unsigned int u = a.u;
    return (unsigned short)((u + 0x7FFFu + ((u >> 16) & 1u)) >> 16);  // RNE
}

__device__ inline bf16x8 cvt8(const float* src) {
    float v[8];
    *reinterpret_cast<float4*>(&v[0]) = *reinterpret_cast<const float4*>(src);
    *reinterpret_cast<float4*>(&v[4]) = *reinterpret_cast<const float4*>(src + 4);
    bf16x8 r;
    #pragma unroll
    for (int j = 0; j < 8; ++j) r[j] = (short)f2bf(v[j]);
    return r;
}

// 16 coherent (L1/L2-bypass, L3-served) 16B loads at base + j*64 bytes.
#define ISSUE16(arr, base)                                                     \
    {                                                                          \
        _Pragma("unroll")                                                      \
        for (int j = 0; j < 16; ++j) {                                         \
            asm volatile("global_load_dwordx4 %0, %1, off offset:%2 sc0 sc1"   \
                         : "=&v"(arr[j])                                       \
                         : "v"(base), "i"(j * 64));                            \
        }                                                                      \
    }
#define PIN16(arr)                                                             \
    {                                                                          \
        _Pragma("unroll")                                                      \
        for (int j = 0; j < 16; ++j) asm volatile("" : "+v"(arr[j]));          \
    }
#define WAITV(N) asm volatile("s_waitcnt vmcnt(" #N ")" ::: "memory")

// ---- one-time prep: WcatT[n][k] = bf16( k<512 ? Wk[k][n] : Wr[k-512][n] ) ----
__global__ void wprep(const float* __restrict__ Wk, const float* __restrict__ Wr,
                      unsigned short* __restrict__ WcatT) {
    __shared__ unsigned short S[32][33];
    const int kb = blockIdx.x * 32;
    const int nb = blockIdx.y * 32;
    const int tx = threadIdx.x;
    const int ty = threadIdx.y;
    #pragma unroll
    for (int j = 0; j < 4; ++j) {
        const int r = ty + 8 * j;
        const int k = kb + r;
        const int n = nb + tx;
        const float v = (k < D_) ? Wk[(size_t)k * N3U + n]
                                 : Wr[(size_t)(k - D_) * N3U + n];
        S[tx][r] = f2bf(v);
    }
    __syncthreads();
    #pragma unroll
    for (int j = 0; j < 4; ++j) {
        const int r = ty + 8 * j;
        WcatT[(size_t)(nb + r) * K_TOT + kb + tx] = S[r][tx];
    }
}

// ---- one-time prep: decays[b][t] = 1/log(e + dt) ----
__global__ void dprep(const float* __restrict__ dts, float* __restrict__ decays) {
    const int i = blockIdx.x * 256 + threadIdx.x;
    if (i < B_ * T_) decays[i] = 1.0f / logf(E_CONST + dts[i]);
}

// ---- persistent kernel: autonomous waves + R9 flag protocol ----
// 256 blocks (XCD-clustered), 128 thr = 2 autonomous waves.
// Wave (bg, bt) owns rows [bg*32+bt*16, +16) x u-tile [ub*16, +16):
//   x-GEMM -> poll 64 producer flags (1 lane per 64B line, 64 readers/line)
//   -> batched quiescent gather (K=1024, counted vmcnt halves)
//   -> 96 h-MFMAs (3 gates share one gather) -> in-wave epilogue
//   -> packed atomic-AGENT publish (merging, L3-resident) -> vmcnt(0) -> flag.
// No barriers in the t-loop; no sentinels; no poison; no retry loads.
__global__ __launch_bounds__(128) void tgru_hyb(
    const float* __restrict__ seq,            // [B,T,D] fp32
    const float* __restrict__ decays,         // [B,T]
    const unsigned short* __restrict__ WcatT, // [3072][1536] bf16
    const float* __restrict__ ib,             // [3U]
    const float* __restrict__ rb,             // [3U]
    unsigned short* hbA,                      // h*dec bf16 (h at even t)
    unsigned short* hbB,                      // h at odd t
    unsigned int* flags,                      // [8 sets][64 blocks] x 64 B
    float* __restrict__ out)                  // [B,U]
{
    extern __shared__ char lds[];

    const int tid  = threadIdx.x;
    const int lane = tid & 63;
    const int bt   = tid >> 6;     // 0..1 (autonomous wave)
    const int l15  = lane & 15;
    const int lk   = lane >> 4;
    const int bid  = blockIdx.x;
    const int bg   = (bid >> 1) & 3;                 // XCD-clustered group
    const int ub   = ((bid >> 3) << 1) | (bid & 1);  // 0..63
    const int u0   = ub * 16;
    const int u    = u0 + l15;
    const int b_base = bg * 32 + bt * 16;
    const int fset = (bg << 1) | bt;                 // flag set 0..7

    // ---- stage weights: 48 rows x 1536 k into LDS, once ----
    for (int idx = tid; idx < WROWS * 192; idx += 128) {
        const int c = idx / 192;
        const int o = idx % 192;
        const unsigned short* src =
            WcatT + (size_t)((c >> 4) * U_ + u0 + (c & 15)) * K_TOT + o * 8;
        *reinterpret_cast<bf16x8*>(lds + (size_t)c * ROWB + o * 16) =
            *reinterpret_cast<const bf16x8*>(src);
    }
    __syncthreads();   // the only barrier in the kernel

    const char* wz = lds + (size_t)(0  + l15) * ROWB + 16 * lk;
    const char* wr = lds + (size_t)(16 + l15) * ROWB + 16 * lk;
    const char* wh = lds + (size_t)(32 + l15) * ROWB + 16 * lk;

    const float bzs  = ib[u] + rb[u];
    const float brs  = ib[U_ + u] + rb[U_ + u];
    const float ibh_ = ib[2 * U_ + u];
    const float rbh_ = rb[2 * U_ + u];

    float hreg[4] = {0.f, 0.f, 0.f, 0.f};   // fp32 h*dec, own (rows, u)

    unsigned int* myflag = flags + (fset * 64 + ub) * 16;        // own line
    const unsigned int* pollp = flags + (fset * 64 + lane) * 16; // 1 lane/line

    #pragma unroll 1
    for (int t = 0; t < T_; ++t) {
        const unsigned short* hbp = (t & 1) ? hbB : hbA;   // h(t)
        unsigned short*       hbn = (t & 1) ? hbA : hbB;   // h(t+1)

        f32x4 az  = {0.f,0.f,0.f,0.f}, ar  = {0.f,0.f,0.f,0.f};
        f32x4 ahx = {0.f,0.f,0.f,0.f}, ahr = {0.f,0.f,0.f,0.f};
        float decn[4];

        // ---- x-GEMM (K 0..512), 3 gates; fills time before h(t) arrives ----
        {
            const float* ap = seq + ((size_t)(b_base + l15) * T_ + t) * D_ + 8 * lk;
            #pragma unroll 4
            for (int j = 0; j < 16; ++j) {
                const bf16x8 a = cvt8(ap + 32 * j);
                az  = __builtin_amdgcn_mfma_f32_16x16x32_bf16(
                    a, *reinterpret_cast<const bf16x8*>(wz + 64 * j), az, 0, 0, 0);
                ar  = __builtin_amdgcn_mfma_f32_16x16x32_bf16(
                    a, *reinterpret_cast<const bf16x8*>(wr + 64 * j), ar, 0, 0, 0);
                ahx = __builtin_amdgcn_mfma_f32_16x16x32_bf16(
                    a, *reinterpret_cast<const bf16x8*>(wh + 64 * j), ahx, 0, 0, 0);
            }
            const int tn = (t < T_ - 1) ? t + 1 : t;
            #pragma unroll
            for (int q = 0; q < 4; ++q)
                decn[q] = decays[(b_base + 4 * lk + q) * T_ + tn];
        }

        if (t > 0) {
            // ---- tight poll: all 64 producers of this (bg, bt) row-set ----
            {
                int guard = 0;
                for (;;) {
                    const unsigned int v = __hip_atomic_load(
                        pollp, __ATOMIC_RELAXED, __HIP_MEMORY_SCOPE_AGENT);
                    if (__all((int)(v >= (unsigned int)t))) break;
                    if (++guard > POLL_LIM) break;   // safety: no hang
                }
                __builtin_amdgcn_fence(__ATOMIC_ACQUIRE, "workgroup");
            }
            // ---- quiescent batched gather: K=1024, two counted halves ----
            const char* hbase =
                (const char*)(hbp + (size_t)(b_base + l15) * U_ + 8 * lk);
            bf16x8 hv1[16], hv2[16];
            ISSUE16(hv1, hbase)
            ISSUE16(hv2, hbase + 1024)

            WAITV(16); PIN16(hv1)
            #pragma unroll 4
            for (int j = 0; j < 16; ++j) {
                const int o = 1024 + 64 * j;
                az  = __builtin_amdgcn_mfma_f32_16x16x32_bf16(
                    hv1[j], *reinterpret_cast<const bf16x8*>(wz + o), az, 0, 0, 0);
                ar  = __builtin_amdgcn_mfma_f32_16x16x32_bf16(
                    hv1[j], *reinterpret_cast<const bf16x8*>(wr + o), ar, 0, 0, 0);
                ahr = __builtin_amdgcn_mfma_f32_16x16x32_bf16(
                    hv1[j], *reinterpret_cast<const bf16x8*>(wh + o), ahr, 0, 0, 0);
            }
            WAITV(0); PIN16(hv2)
            #pragma unroll 4
            for (int j = 0; j < 16; ++j) {
                const int o = 2048 + 64 * j;
                az  = __builtin_amdgcn_mfma_f32_16x16x32_bf16(
                    hv2[j], *reinterpret_cast<const bf16x8*>(wz + o), az, 0, 0, 0);
                ar  = __builtin_amdgcn_mfma_f32_16x16x32_bf16(
                    hv2[j], *reinterpret_cast<const bf16x8*>(wr + o), ar, 0, 0, 0);
                ahr = __builtin_amdgcn_mfma_f32_16x16x32_bf16(
                    hv2[j], *reinterpret_cast<const bf16x8*>(wh + o), ahr, 0, 0, 0);
            }
        }

        // ---- in-wave epilogue ----
        float hn[4];
        #pragma unroll
        for (int q = 0; q < 4; ++q) {
            const float z  = 1.0f / (1.0f + expf(-(az[q] + bzs)));
            const float r  = 1.0f / (1.0f + expf(-(ar[q] + brs)));
            const float hh = tanhf(ahx[q] + ibh_ + r * (ahr[q] + rbh_));
            hn[q] = z * hreg[q] + (1.0f - z) * hh;
        }
        if (t == T_ - 1) {
            #pragma unroll
            for (int q = 0; q < 4; ++q)
                out[(size_t)(b_base + 4 * lk + q) * U_ + u] = hn[q];
        } else {
            unsigned int pk[4];
            #pragma unroll
            for (int q = 0; q < 4; ++q) {
                const float hd = hn[q] * decn[q];
                hreg[q] = hd;
                const float po = __shfl_xor(hd, 1);   // partner u (odd lane)
                pk[q] = (unsigned int)f2bf(hd) | ((unsigned int)f2bf(po) << 16);
            }
            if ((lane & 1) == 0) {
                #pragma unroll
                for (int q = 0; q < 4; ++q) {
                    unsigned int* pa = (unsigned int*)(hbn
                        + (size_t)(b_base + 4 * lk + q) * U_ + u);
                    __hip_atomic_store(pa, pk[q], __ATOMIC_RELAXED,
                                       __HIP_MEMORY_SCOPE_AGENT);
                }
            }
            WAITV(0);   // publishes at L3 (merging path — 70 MB proven, R9)
            if (lane == 0) {
                __hip_atomic_store(myflag, (unsigned int)(t + 1),
                                   __ATOMIC_RELAXED, __HIP_MEMORY_SCOPE_AGENT);
            }
        }
    }
}

extern "C" void kernel_launch(void* const* d_in, const int* in_sizes, int n_in,
                              void* d_out, int out_size, void* d_ws, size_t ws_size,
                              hipStream_t stream) {
    const float* seq = (const float*)d_in[0];
    const float* dts = (const float*)d_in[1];
    const float* Wk  = (const float*)d_in[2];
    const float* Wr  = (const float*)d_in[3];
    const float* ib  = (const float*)d_in[4];
    const float* rb  = (const float*)d_in[5];
    float* out = (float*)d_out;

    char* wsb = (char*)d_ws;
    // ws layout (bytes):
    //   [0,        9437184)   WcatT bf16 [3072][1536]
    //   [9437184,  9568256)   decays fp32 [128][256]
    //   [9568256,  9830400)   hbA bf16 [128][1024]  (not read at t=0)
    //   [9830400, 10092544)   hbB
    //   [10092544,10125312)   flags: 8 sets x 64 blocks x 64 B
    unsigned short* wcat   = (unsigned short*)(wsb);
    float*          decays = (float*)(wsb + 9437184);
    unsigned short* hbA    = (unsigned short*)(wsb + 9568256);
    unsigned short* hbB    = (unsigned short*)(wsb + 9830400);
    unsigned int*   flags  = (unsigned int*)(wsb + 10092544);

    // flags must be 0 at start of every replay (monotonic within a launch)
    hipMemsetAsync(flags, 0, 32768, stream);

    wprep<<<dim3(K_TOT / 32, N3U / 32), dim3(32, 8), 0, stream>>>(Wk, Wr, wcat);
    dprep<<<dim3((B_ * T_ + 255) / 256), dim3(256), 0, stream>>>(dts, decays);

    hipFuncSetAttribute((const void*)tgru_hyb,
                        hipFuncAttributeMaxDynamicSharedMemorySize, LDS_BYTES);

    tgru_hyb<<<dim3(256), dim3(128), LDS_BYTES, stream>>>(
        seq, decays, wcat, ib, rb, hbA, hbB, flags, out);
}